// Round 8
// baseline (2660.416 us; speedup 1.0000x reference)
//
#include <hip/hip_runtime.h>

#define B_ 128
#define T_ 2048
#define H_ 128
#define IN_ 6
#define CHUNK_ 32
#define NCHUNK_ 64
#define FLAG_STRIDE_ 64
#define HS_ 144
#define XGSLOT_ (CHUNK_ * 8192)   // 1 MiB of floats per ring slot
#define XGRING_ 2                 // depth-2 rings (24 rings x 2 MiB = 48 MiB)
#define NFLAGS_ 184  // fh 0..63 = l*32+sl (l<2); fx 64..87 = 64+gl*8+bg; fc 88..183 = 88+gl*32+sl

typedef _Float16 f16x8 __attribute__((ext_vector_type(8)));
typedef float    f32x4 __attribute__((ext_vector_type(4)));

__device__ __forceinline__ unsigned short f2h_u(float f) {
  union { _Float16 h; unsigned short u; } v; v.h = (_Float16)f; return v.u;
}
__device__ __forceinline__ unsigned int pack2(float a, float b) {
  return (unsigned int)f2h_u(a) | ((unsigned int)f2h_u(b) << 16);
}
__device__ __forceinline__ float sigf_(float x) {
  return __builtin_amdgcn_rcpf(1.0f + __expf(-x));
}
__device__ __forceinline__ float tanhf_(float x) {
  return 2.0f * __builtin_amdgcn_rcpf(1.0f + __expf(-2.0f * x)) - 1.0f;
}
__device__ __forceinline__ f16x8 load_w8(const float* __restrict__ p) {
  f16x8 r;
#pragma unroll
  for (int i = 0; i < 8; ++i) r[i] = (_Float16)p[i];
  return r;
}

__global__ void init_flags(unsigned int* flags) {
  flags[blockIdx.x * 256 + threadIdx.x] = 0u;  // grid 46 -> 11776 = 184 * 64
}

#define MFMA16(A, B, C) __builtin_amdgcn_mfma_f32_16x16x32_f16((A), (B), (C), 0, 0, 0)

// ---------------------------------------------------------------------------
// R20: two independent batch-4 chains per 512-thread WG, decoupled by 4-wave
// LDS soft-barriers (no workgroup s_barrier in the hot loop). While chain A
// runs its serial skeleton (act -> ds_write h -> barrier -> ds_read h), chain
// B's MFMAs keep the matrix pipe fed: target window = per-SIMD MFMA issue
// (2 waves x 32 = 1240cy per step-PAIR) instead of R16's serial 1806/step.
//  - 48 rec WGs: layer=bid>>4, pair=bid&15; chain=wv>>2; sl=pair*2+chain.
//    Wave w of a chain owns h-rows [32w,32w+32): 8 row-tiles x 4 kc = 32 MFMA.
//  - Mirror-4 cols (4 unique batches), act = 2 values/lane.
//  - All 3 layers consume xg rings; layer-0 GEMM offloaded to gl=0 producers
//    (R19-proven, bit-identical). Producers/flags/rings byte-identical to R19.
// ---------------------------------------------------------------------------
__global__ __launch_bounds__(512, 2)
void lstm_pipe(const float* __restrict__ x,
               const float* __restrict__ Wih0, const float* __restrict__ Whh0,
               const float* __restrict__ bih0, const float* __restrict__ bhh0,
               const float* __restrict__ Wih1, const float* __restrict__ Whh1,
               const float* __restrict__ bih1, const float* __restrict__ bhh1,
               const float* __restrict__ Wih2, const float* __restrict__ Whh2,
               const float* __restrict__ bih2, const float* __restrict__ bhh2,
               unsigned short* __restrict__ region,   // f16 [B][T][128]
               float* __restrict__ xg,                // 24 rings [gl*8+bg][2][XGSLOT_]
               unsigned int* __restrict__ state_h,    // [B][64] f16x2
               unsigned int* __restrict__ flags)
{
  const int bid  = blockIdx.x;
  const int tid  = threadIdx.x;
  const int lane = tid & 63;
  const int wv   = tid >> 6;    // wave 0..7
  const int n16  = lane & 15;
  const int quad = lane >> 4;

  __shared__ unsigned short smem[32 * 16 * HS_];   // 147456 B (producer max)
  __shared__ int sbar[2];
  __shared__ int s_have;

#define WAITP(ptr_, need_, have_)                                   \
  do {                                                              \
    if ((have_) < (need_)) {                                        \
      if (tid == 0) {                                               \
        int v = (int)__hip_atomic_load(ptr_, __ATOMIC_RELAXED,      \
                                       __HIP_MEMORY_SCOPE_AGENT);   \
        while (v < (need_)) {                                       \
          __builtin_amdgcn_s_sleep(2);                              \
          v = (int)__hip_atomic_load(ptr_, __ATOMIC_RELAXED,        \
                                     __HIP_MEMORY_SCOPE_AGENT);     \
        }                                                           \
        (void)__hip_atomic_load(ptr_, __ATOMIC_ACQUIRE,             \
                                __HIP_MEMORY_SCOPE_AGENT);          \
        s_have = v;                                                 \
      }                                                             \
      __syncthreads();                                              \
      (have_) = s_have;                                             \
    }                                                               \
  } while (0)

  if (bid >= 48) {
    // ======================= producer roles (R19-proven) =================
    const int gi = bid - 48;
    const int gl = gi >> 3;        // 0,1,2 : produces xg for layer gl
    const int bg = gi & 7;
    float* xgo = xg + (size_t)(gl * 8 + bg) * (XGRING_ * (size_t)XGSLOT_);
    unsigned int* fx_out = &flags[(64 + gl * 8 + bg) * FLAG_STRIDE_];
    unsigned int* fcp[4];
#pragma unroll
    for (int q = 0; q < 4; ++q)
      fcp[q] = &flags[(88 + gl * 32 + 4 * bg + q) * FLAG_STRIDE_];

    if (gl == 0) {
      // ---- layer-0 input GEMM: xg0 = bias0 + Wih0 . x ----
      f16x8 wih[4];
#pragma unroll
      for (int j = 0; j < 4; ++j)
#pragma unroll
        for (int i = 0; i < 8; ++i) wih[j][i] = (_Float16)0.f;
      if (quad == 0) {
#pragma unroll
        for (int j = 0; j < 4; ++j) {
          const float* p = Wih0 + (size_t)(j * 128 + 16 * wv + n16) * IN_;
#pragma unroll
          for (int i = 0; i < IN_; ++i) wih[j][i] = (_Float16)p[i];
        }
      }
      f32x4 bias4[4];
#pragma unroll
      for (int j = 0; j < 4; ++j)
#pragma unroll
        for (int r = 0; r < 4; ++r) {
          int row = j * 128 + 16 * wv + quad * 4 + r;
          bias4[j][r] = bih0[row] + bhh0[row];
        }
      unsigned short* xbp = smem;                 // [32 t][16 b][8]
      const int tt = tid >> 4, bb = tid & 15;
      int hc0 = 0, hc1 = 0, hc2 = 0, hc3 = 0;
      for (int k = 0; k < NCHUNK_; ++k) {
        if (k >= XGRING_) {
          WAITP(fcp[0], k - (XGRING_ - 1), hc0);
          WAITP(fcp[1], k - (XGRING_ - 1), hc1);
          WAITP(fcp[2], k - (XGRING_ - 1), hc2);
          WAITP(fcp[3], k - (XGRING_ - 1), hc3);
        }
        {
          const float* xp = x + ((size_t)(bg * 16 + bb) * T_ + (size_t)(CHUNK_ * k + tt)) * IN_;
          uint4 v;
          v.x = pack2(xp[0], xp[1]); v.y = pack2(xp[2], xp[3]);
          v.z = pack2(xp[4], xp[5]); v.w = 0u;
          *(uint4*)&xbp[(tt * 16 + bb) * 8] = v;
        }
        __syncthreads();
        const int slot = k & 1;
        for (int t = 0; t < CHUNK_; ++t) {
          f16x8 xi;
#pragma unroll
          for (int i = 0; i < 8; ++i) xi[i] = (_Float16)0.f;
          if (quad == 0) xi = *(const f16x8*)&xbp[(t * 16 + n16) * 8];
          float* xp = xgo + (size_t)(slot * CHUNK_ + t) * 8192 + quad * 64 + n16 * 4;
#pragma unroll
          for (int j = 0; j < 4; ++j) {
            f32x4 a = MFMA16(wih[j], xi, bias4[j]);
            *(f32x4*)(xp + (size_t)(8 * j + wv) * 256) = a;
          }
        }
        __syncthreads();
        if (tid == 0)
          __hip_atomic_store(fx_out, (unsigned int)(k + 1),
                             __ATOMIC_RELEASE, __HIP_MEMORY_SCOPE_AGENT);
      }
      return;
    }

    // ---- gl = 1,2 : hidden-state GEMM producers ----
    const int b8 = n16 & 7;
    const float* Wih = (gl == 1) ? Wih1 : Wih2;
    const float* bih = (gl == 1) ? bih1 : bih2;
    const float* bhh = (gl == 1) ? bhh1 : bhh2;
    unsigned int* fhp[4];
#pragma unroll
    for (int q = 0; q < 4; ++q)
      fhp[q] = &flags[((gl - 1) * 32 + 4 * bg + q) * FLAG_STRIDE_];

    f16x8 wih[4][4];
#pragma unroll
    for (int j = 0; j < 4; ++j)
#pragma unroll
      for (int kc = 0; kc < 4; ++kc)
        wih[j][kc] = load_w8(Wih + (size_t)(j * 128 + 16 * wv + n16) * H_ + kc * 32 + quad * 8);
    f32x4 bias4[4];
#pragma unroll
    for (int j = 0; j < 4; ++j)
#pragma unroll
      for (int r = 0; r < 4; ++r) {
        int row = j * 128 + 16 * wv + quad * 4 + r;
        bias4[j][r] = bih[row] + bhh[row];
      }

    int hh0 = 0, hh1 = 0, hh2 = 0, hh3 = 0;
    int hc0 = 0, hc1 = 0, hc2 = 0, hc3 = 0;
    const int tt = tid >> 4, bb = tid & 15;
    const int swk = bb & 7;
    for (int k = 0; k < NCHUNK_; ++k) {
      WAITP(fhp[0], k + 1, hh0);
      WAITP(fhp[1], k + 1, hh1);
      WAITP(fhp[2], k + 1, hh2);
      WAITP(fhp[3], k + 1, hh3);
      if (k >= XGRING_) {
        WAITP(fcp[0], k - (XGRING_ - 1), hc0);
        WAITP(fcp[1], k - (XGRING_ - 1), hc1);
        WAITP(fcp[2], k - (XGRING_ - 1), hc2);
        WAITP(fcp[3], k - (XGRING_ - 1), hc3);
      }
      {
        const uint4* gp = (const uint4*)(region +
            ((size_t)(bg * 16 + bb) * T_ + (size_t)(CHUNK_ * k + tt)) * H_);
        uint4* lp = (uint4*)&smem[(tt * 16 + bb) * HS_];
#pragma unroll
        for (int i = 0; i < 16; ++i) lp[i ^ swk] = gp[i];
      }
      __syncthreads();
      const int slot = k & 1;
      for (int t = 0; t < CHUNK_; ++t) {
        f16x8 hi4[4];
#pragma unroll
        for (int kc = 0; kc < 4; ++kc)
          hi4[kc] = *(const f16x8*)&smem[(t * 16 + n16) * HS_ +
                                         ((kc * 32 + quad * 8) ^ (b8 << 3))];
        float* xp = xgo + (size_t)(slot * CHUNK_ + t) * 8192 + quad * 64 + n16 * 4;
#pragma unroll
        for (int j = 0; j < 4; ++j) {
          f32x4 a = bias4[j];
#pragma unroll
          for (int kc = 0; kc < 4; ++kc)
            a = MFMA16(wih[j][kc], hi4[kc], a);
          *(f32x4*)(xp + (size_t)(8 * j + wv) * 256) = a;
        }
      }
      __syncthreads();
      if (tid == 0)
        __hip_atomic_store(fx_out, (unsigned int)(k + 1),
                           __ATOMIC_RELEASE, __HIP_MEMORY_SCOPE_AGENT);
    }
    return;
  }

  // ========================= recurrence role =============================
  const int layer = bid >> 4;          // 0..2
  const int chain = wv >> 2;           // 0,1 : independent slice-chain
  const int w     = wv & 3;            // wave within chain
  const int sl    = (bid & 15) * 2 + chain;   // slice 0..31
  const int bcol  = n16 & 3;           // batch column (mirror-4)
  const int rsel  = n16 >> 2;          // owned acc element
  const bool r1 = (rsel & 1) != 0, r2 = (rsel & 2) != 0;
  const int batch = sl * 4 + bcol;
  const float* Whh = (layer == 0) ? Whh0 : ((layer == 1) ? Whh1 : Whh2);

  unsigned short* hst = smem + chain * (2 * 4 * HS_);   // [2][4][HS_] per chain

  // wave owns h-rows [32w, 32w+32): 8 tiles jj = 2*g + ti (g=gate, ti=subtile)
  f16x8 whh[8][4];
#pragma unroll
  for (int jj = 0; jj < 8; ++jj) {
    const int g = jj >> 1, ti = jj & 1;
#pragma unroll
    for (int kc = 0; kc < 4; ++kc)
      whh[jj][kc] = load_w8(Whh + (size_t)(g * 128 + 32 * w + 16 * ti + n16) * H_
                            + kc * 32 + quad * 8);
  }

  // zero both chains' hstate (first 2*1152 shorts of smem)
  for (int i = tid; i < 2 * (2 * 4 * HS_) / 2; i += 512) ((unsigned int*)smem)[i] = 0u;
  if (tid < 2) sbar[tid] = 0;

  const int hr0 = 32 * w + 4 * quad + rsel;  // owned h rows (ti=0 / ti=1)
  const int hr1 = hr0 + 16;
  const int wsw0 = ((((hr0 >> 3) ^ bcol) << 3) | (hr0 & 7));
  const int wsw1 = ((((hr1 >> 3) ^ bcol) << 3) | (hr1 & 7));
  unsigned short* regp0 = region + (size_t)batch * T_ * H_ + hr0;
  unsigned short* regp1 = region + (size_t)batch * T_ * H_ + hr1;

  const float* xgi = xg + (size_t)(layer * 8 + (sl >> 2)) * (XGRING_ * (size_t)XGSLOT_);
  const int lane_off = quad * 64 + ((sl & 3) * 4 + bcol) * 4;
  int rtoff[8];
#pragma unroll
  for (int jj = 0; jj < 8; ++jj)
    rtoff[jj] = (8 * (jj >> 1) + 2 * w + (jj & 1)) * 256;

  unsigned int* fx_in  = &flags[(64 + layer * 8 + (sl >> 2)) * FLAG_STRIDE_];
  unsigned int* fc_out = &flags[(88 + layer * 32 + sl) * FLAG_STRIDE_];
  unsigned int* fh_out = (layer < 2) ? &flags[(layer * 32 + sl) * FLAG_STRIDE_] : nullptr;

  float c0 = 0.f, c1 = 0.f;
  unsigned short dh0[8], dh1[8];
  f32x4 xr[8];
  int have_x = 0, phase = 0;

  // per-wave agent-flag spin (no workgroup sync)
#define WAITW(ptr_, need_)                                          \
  do {                                                              \
    if (have_x < (need_)) {                                         \
      int v;                                                        \
      do {                                                          \
        v = (int)__hip_atomic_load(ptr_, __ATOMIC_RELAXED,          \
                                   __HIP_MEMORY_SCOPE_AGENT);       \
        if (v < (need_)) __builtin_amdgcn_s_sleep(1);               \
      } while (v < (need_));                                        \
      (void)__hip_atomic_load(ptr_, __ATOMIC_ACQUIRE,               \
                              __HIP_MEMORY_SCOPE_AGENT);            \
      have_x = v;                                                   \
    }                                                               \
  } while (0)

  // 4-wave chain soft-barrier: monotonic LDS counter, broadcast spin
#define CHAIN_BAR()                                                 \
  do {                                                              \
    ++phase;                                                        \
    asm volatile("s_waitcnt lgkmcnt(0)" ::: "memory");              \
    if (lane == 0)                                                  \
      __hip_atomic_fetch_add(&sbar[chain], 1, __ATOMIC_RELAXED,     \
                             __HIP_MEMORY_SCOPE_WORKGROUP);         \
    while (__hip_atomic_load(&sbar[chain], __ATOMIC_RELAXED,        \
                             __HIP_MEMORY_SCOPE_WORKGROUP) < 4 * phase) {} \
    __builtin_amdgcn_sched_barrier(0);                              \
  } while (0)

#define SEL3(a_) (r1 ? (r2 ? (a_)[3] : (a_)[1]) : (r2 ? (a_)[2] : (a_)[0]))

  // prologue: xg for t=0 (slot 0)
  WAITW(fx_in, 1);
#pragma unroll
  for (int jj = 0; jj < 8; ++jj)
    xr[jj] = *(const f32x4*)(xgi + (size_t)rtoff[jj] + lane_off);
  __syncthreads();  // hstate zeros + sbar init (one-time full barrier)

  const float* cb = xgi;   // current chunk slot base
  for (int g = 0; g < 256; ++g) {
#pragma unroll
    for (int s = 0; s < 8; ++s) {
      const int t = 8 * g + s;
      const int rp = t & 1, wp = rp ^ 1;
      f16x8 hs[4];
#pragma unroll
      for (int kc = 0; kc < 4; ++kc)
        hs[kc] = *(const f16x8*)&hst[(rp * 4 + bcol) * HS_ +
                                     ((kc * 32 + quad * 8) ^ (bcol << 3))];
      f32x4 a[8];
#pragma unroll
      for (int jj = 0; jj < 8; ++jj) a[jj] = MFMA16(whh[jj][0], hs[0], xr[jj]);
#pragma unroll
      for (int kc = 1; kc < 4; ++kc)
#pragma unroll
        for (int jj = 0; jj < 8; ++jj)
          a[jj] = MFMA16(whh[jj][kc], hs[kc], a[jj]);
      // prefetch xg for t+1 (xr consumed above); chunk crossing waits flag
      const int tn = t + 1;
      if (tn < 2048) {
        if ((tn & 31) == 0) {
          const int c2 = tn >> 5;
          WAITW(fx_in, c2 + 1);
          cb = xgi + (size_t)(c2 & 1) * XGSLOT_;
        }
        const float* p = cb + (size_t)(tn & 31) * 8192 + lane_off;
#pragma unroll
        for (int jj = 0; jj < 8; ++jj)
          xr[jj] = *(const f32x4*)(p + rtoff[jj]);
      }
      // act: 2 owned h values (ti = 0,1)
      {
        float vi = SEL3(a[0]), vf = SEL3(a[2]), vg = SEL3(a[4]), vo = SEL3(a[6]);
        float i_ = sigf_(vi), f_ = sigf_(vf), t_ = tanhf_(vg), o_ = sigf_(vo);
        c0 = f_ * c0 + i_ * t_;
        unsigned short uh = f2h_u(o_ * tanhf_(c0));
        dh0[s] = uh;
        hst[(wp * 4 + bcol) * HS_ + wsw0] = uh;
      }
      {
        float vi = SEL3(a[1]), vf = SEL3(a[3]), vg = SEL3(a[5]), vo = SEL3(a[7]);
        float i_ = sigf_(vi), f_ = sigf_(vf), t_ = tanhf_(vg), o_ = sigf_(vo);
        c1 = f_ * c1 + i_ * t_;
        unsigned short uh = f2h_u(o_ * tanhf_(c1));
        dh1[s] = uh;
        hst[(wp * 4 + bcol) * HS_ + wsw1] = uh;
      }
      CHAIN_BAR();
    }
    // group end: deferred region stores (stay in flight until publish)
    if (layer < 2) {
#pragma unroll
      for (int s = 0; s < 8; ++s) {
        regp0[(size_t)(8 * g + s) * H_] = dh0[s];
        regp1[(size_t)(8 * g + s) * H_] = dh1[s];
      }
    }
    if ((g & 3) == 3) {
      asm volatile("s_waitcnt vmcnt(0)" ::: "memory");  // per-wave drain
      CHAIN_BAR();                                       // all 4 waves drained
      if (lane == 0 && w == 0) {
        unsigned int cdone = (unsigned int)((g >> 2) + 1);
        if (layer < 2)
          __hip_atomic_store(fh_out, cdone, __ATOMIC_RELEASE, __HIP_MEMORY_SCOPE_AGENT);
        __hip_atomic_store(fc_out, cdone, __ATOMIC_RELEASE, __HIP_MEMORY_SCOPE_AGENT);
      }
    }
  }
  if (layer == 2) {
    ((unsigned short*)state_h)[(size_t)batch * 128 + hr0] = dh0[7];
    ((unsigned short*)state_h)[(size_t)batch * 128 + hr1] = dh1[7];
  }
#undef SEL3
#undef CHAIN_BAR
#undef WAITW
#undef WAITP
}

// ---------------------------------------------------------------------------
__global__ void head_kernel(const unsigned int* __restrict__ state_h,
                            const float* __restrict__ Wout,
                            const float* __restrict__ bout,
                            float* __restrict__ out)
{
  int b = threadIdx.x;  // 128 threads, 1 block
  float s = bout[0];
  for (int j = 0; j < 64; ++j) {
    unsigned int p = state_h[b * 64 + j];
    union { unsigned short u; _Float16 h; } lo, hi;
    lo.u = (unsigned short)(p & 0xffffu);
    hi.u = (unsigned short)(p >> 16);
    s += (float)lo.h * Wout[2 * j] + (float)hi.h * Wout[2 * j + 1];
  }
  out[b] = s;
}

// ---------------------------------------------------------------------------
extern "C" void kernel_launch(void* const* d_in, const int* in_sizes, int n_in,
                              void* d_out, int out_size, void* d_ws, size_t ws_size,
                              hipStream_t stream)
{
  const float* x = (const float*)d_in[0];
  const float* Wih[3] = {(const float*)d_in[1], (const float*)d_in[5], (const float*)d_in[9]};
  const float* Whh[3] = {(const float*)d_in[2], (const float*)d_in[6], (const float*)d_in[10]};
  const float* bih[3] = {(const float*)d_in[3], (const float*)d_in[7], (const float*)d_in[11]};
  const float* bhh[3] = {(const float*)d_in[4], (const float*)d_in[8], (const float*)d_in[12]};
  const float* Wout = (const float*)d_in[13];
  const float* bout = (const float*)d_in[14];
  float* out = (float*)d_out;

  char* ws = (char*)d_ws;
  size_t off = 0;
  unsigned short* region = (unsigned short*)(ws + off); off += (size_t)B_ * T_ * H_ * 2;            // 64 MiB
  float* xg = (float*)(ws + off);                       off += (size_t)24 * XGRING_ * XGSLOT_ * 4;  // 48 MiB
  unsigned int* state_h  = (unsigned int*)(ws + off);   off += (size_t)B_ * 64 * 4;
  off = (off + 255) & ~(size_t)255;
  unsigned int* flags    = (unsigned int*)(ws + off);   off += NFLAGS_ * FLAG_STRIDE_ * 4;

  init_flags<<<46, 256, 0, stream>>>(flags);
  lstm_pipe<<<72, 512, 0, stream>>>(x,
      Wih[0], Whh[0], bih[0], bhh[0],
      Wih[1], Whh[1], bih[1], bhh[1],
      Wih[2], Whh[2], bih[2], bhh[2],
      region, xg, state_h, flags);
  head_kernel<<<1, 128, 0, stream>>>(state_h, Wout, bout, out);
}